// Round 1
// 124.877 us; speedup vs baseline: 1.0180x; 1.0180x over previous
//
#include <hip/hip_runtime.h>

// Problem constants: bs=8, Na=128, Nc=256, CS=3, D=H=64, Z=8, NT=3, NET=9
// Output 0: logpi (8,256,8,8,8) f32 = 1048576 elems
// Output 1: z meshgrid (8,8,8,3) -> 1536 elems (float values)

#define BS   8
#define NA   128
#define NC   256
#define DIM  64
#define ZZ   8

// ws layout: [0, 32KB) node_factor (8*128*8 f32).  ef buffer no longer needed.

// ---------------------------------------------------------------------------
// Kernel A: node MLP, one block (256 thr, split-K x4) per (b,n). (unchanged)
// ---------------------------------------------------------------------------
__global__ __launch_bounds__(256) void node_mlp_kernel(
    const int* __restrict__ nt, const float* __restrict__ enc,
    const float* __restrict__ W0, const float* __restrict__ b0,
    const float* __restrict__ W1, const float* __restrict__ b1,
    const float* __restrict__ W2, const float* __restrict__ b2,
    float* __restrict__ nf) {
  const int blk = blockIdx.x;          // b*NA + n
  const int tid = threadIdx.x;
  const int j = tid & 63, s = tid >> 6;  // wave s handles K-slice s
  const int t = nt[blk];

  __shared__ float e[DIM];
  __shared__ float h[DIM];
  __shared__ float red[4][DIM];
  __shared__ float red2[8][ZZ];

  if (tid < DIM) e[tid] = enc[blk * DIM + tid];
  __syncthreads();

  // layer 0: e -> h (relu)
  {
    float a = 0.f;
    const float* w = W0 + t * DIM * DIM + s * 16 * DIM + j;
#pragma unroll
    for (int k = 0; k < 16; ++k) a = fmaf(e[s * 16 + k], w[k * DIM], a);
    red[s][j] = a;
  }
  __syncthreads();
  if (s == 0) {
    float v = red[0][j] + red[1][j] + red[2][j] + red[3][j] + b0[t * DIM + j];
    h[j] = fmaxf(v, 0.f);
  }
  __syncthreads();

  // layer 1: h -> e (relu)
  {
    float a = 0.f;
    const float* w = W1 + t * DIM * DIM + s * 16 * DIM + j;
#pragma unroll
    for (int k = 0; k < 16; ++k) a = fmaf(h[s * 16 + k], w[k * DIM], a);
    red[s][j] = a;
  }
  __syncthreads();
  if (s == 0) {
    float v = red[0][j] + red[1][j] + red[2][j] + red[3][j] + b1[t * DIM + j];
    e[j] = fmaxf(v, 0.f);
  }
  __syncthreads();

  // layer 2: e (64) -> nf (8); threads 0..63, split-K x8
  if (tid < DIM) {
    const int j2 = tid & 7, s2 = tid >> 3;   // s2: 0..7
    float a = 0.f;
    const float* w = W2 + t * DIM * ZZ + s2 * 8 * ZZ + j2;
#pragma unroll
    for (int k = 0; k < 8; ++k) a = fmaf(e[s2 * 8 + k], w[k * ZZ], a);
    red2[s2][j2] = a;
  }
  __syncthreads();
  if (tid < ZZ) {
    float v = b2[t * ZZ + tid];
#pragma unroll
    for (int s2 = 0; s2 < 8; ++s2) v += red2[s2][tid];
    nf[blk * ZZ + tid] = v;
  }
}

// ---------------------------------------------------------------------------
// Wave-level 64x64 matvec: input x[j] held by lane j, output y[j] returned to
// lane j.  Each lane owns 4 outputs (j4 = (lane&15)*4) over a 16-wide K-slice
// (ks = lane>>4), loading weights as float4 (16 x dwordx4 per layer instead of
// 64 x dword).  Cross-slice reduce via shfl_xor(16/32), then shfl scatter back
// to one-output-per-lane.  No LDS, no barriers.
// ---------------------------------------------------------------------------
__device__ __forceinline__ float mv64(float v, const float* __restrict__ W,
                                      const float* __restrict__ B, int lane,
                                      bool relu) {
  const int j4 = (lane & 15) * 4;   // output group
  const int ks = lane >> 4;         // k-slice 0..3
  float ax = 0.f, ay = 0.f, az = 0.f, aw = 0.f;
#pragma unroll 8
  for (int i = 0; i < 16; ++i) {
    const int k = ks * 16 + i;
    const float vk = __shfl(v, k);
    const float4 w4 = *reinterpret_cast<const float4*>(W + k * DIM + j4);
    ax = fmaf(vk, w4.x, ax);
    ay = fmaf(vk, w4.y, ay);
    az = fmaf(vk, w4.z, az);
    aw = fmaf(vk, w4.w, aw);
  }
  // reduce across the 4 k-slices (lane bits 4,5)
  ax += __shfl_xor(ax, 16); ay += __shfl_xor(ay, 16);
  az += __shfl_xor(az, 16); aw += __shfl_xor(aw, 16);
  ax += __shfl_xor(ax, 32); ay += __shfl_xor(ay, 32);
  az += __shfl_xor(az, 32); aw += __shfl_xor(aw, 32);
  // redistribute: lane j wants component (j&3) from class (j>>2); lanes 0..15
  // hold class = lane.
  const int src = lane >> 2;
  const float s0 = __shfl(ax, src);
  const float s1 = __shfl(ay, src);
  const float s2 = __shfl(az, src);
  const float s3 = __shfl(aw, src);
  const int c = lane & 3;
  float r = (c == 0) ? s0 : (c == 1) ? s1 : (c == 2) ? s2 : s3;
  r += B[lane];
  return relu ? fmaxf(r, 0.f) : r;
}

// ---------------------------------------------------------------------------
// Kernel BC: fused edge MLP + assembly.  One block (256 thr = 4 waves) per
// clique.  Waves 0..2 each run one full edge-pair MLP in-wave (shfl matvec);
// wave 3 gathers the 3 node-factor rows.  One barrier, then all 4 waves
// assemble the 512 logpi outputs.
// ---------------------------------------------------------------------------
__global__ __launch_bounds__(256) void edge_assemble_kernel(
    const int* __restrict__ nt, const int* __restrict__ cni,
    const float* __restrict__ edge_enc,
    const float* __restrict__ eW0, const float* __restrict__ eb0,
    const float* __restrict__ eW1, const float* __restrict__ eb1,
    const float* __restrict__ eW2, const float* __restrict__ eb2,
    const float* __restrict__ nf, float* __restrict__ out) {
  const int blk = blockIdx.x;          // b*NC + c
  const int tid = threadIdx.x;
  const int lane = tid & 63, wid = tid >> 6;
  const int b = blk >> 8;

  __shared__ float ef_s[3][DIM];
  __shared__ float nfs[3][ZZ];

  // every wave fetches the 3 clique node indices + types and broadcasts them
  int rawv = (lane < 3) ? cni[blk * 3 + lane] : -1;
  int ivc = (rawv < 0 || rawv >= NA) ? NA : rawv;
  int tt = (ivc < NA) ? nt[b * NA + ivc] : 0;
  const int id0 = __shfl(ivc, 0), id1 = __shfl(ivc, 1), id2 = __shfl(ivc, 2);
  const int tp0 = __shfl(tt, 0), tp1 = __shfl(tt, 1), tp2 = __shfl(tt, 2);

  if (wid < 3) {
    // pairs: wid 0 -> (0,1), 1 -> (0,2), 2 -> (1,2)
    const int pi = (wid == 2) ? 1 : 0;
    const int pj = (wid == 0) ? 1 : 2;
    const int ia = (pi == 0) ? id0 : id1;
    const int jb = (pj == 1) ? id1 : id2;
    float res = 0.f;
    if (ia < NA && jb < NA) {      // uniform across wave
      const int ta = (pi == 0) ? tp0 : tp1;
      const int tb = (pj == 1) ? tp1 : tp2;
      const int t = tb * 3 + ta;   // pa[t]=nt[j], pb[t]=nt[i]
      float v = edge_enc[((size_t)(b * NA + ia) * NA + jb) * DIM + lane];
      v = mv64(v, eW0 + t * DIM * DIM, eb0 + t * DIM, lane, true);
      v = mv64(v, eW1 + t * DIM * DIM, eb1 + t * DIM, lane, true);
      res = mv64(v, eW2 + t * DIM * DIM, eb2 + t * DIM, lane, false);
    }
    ef_s[wid][lane] = res;
  } else if (lane < 3 * ZZ) {
    const int slot = lane >> 3, z = lane & 7;
    const int ix = (slot == 0) ? id0 : (slot == 1) ? id1 : id2;
    nfs[slot][z] = (ix < NA) ? nf[(b * NA + ix) * ZZ + z] : 0.f;
  }
  __syncthreads();

  // assembly: 512 outputs, 2 per thread, coalesced stores
  float* o = out + (size_t)blk * (ZZ * ZZ * ZZ);
#pragma unroll
  for (int r = 0; r < 2; ++r) {
    const int i = r * 256 + tid;
    const int z0 = i >> 6, z1 = (i >> 3) & 7, z2 = i & 7;
    o[i] = nfs[0][z0] + nfs[1][z1] + nfs[2][z2]
         + ef_s[0][z0 * ZZ + z1] + ef_s[1][z0 * ZZ + z2] + ef_s[2][z1 * ZZ + z2];
  }

  // z meshgrid tail: 1536 elems = 3 blocks * 512
  if (blk < 3) {
#pragma unroll
    for (int r = 0; r < 2; ++r) {
      const int i = blk * 512 + r * 256 + tid;
      const int k = i % 3;
      const int rr = i / 3;             // z0*64 + z1*8 + z2
      const int zz2 = rr & 7, zz1 = (rr >> 3) & 7, zz0 = rr >> 6;
      out[BS * NC * ZZ * ZZ * ZZ + i] =
          (float)((k == 0) ? zz0 : (k == 1) ? zz1 : zz2);
    }
  }
}

extern "C" void kernel_launch(void* const* d_in, const int* in_sizes, int n_in,
                              void* d_out, int out_size, void* d_ws, size_t ws_size,
                              hipStream_t stream) {
  const int*   node_types = (const int*)  d_in[0];
  const float* node_enc   = (const float*)d_in[1];
  const float* edge_enc   = (const float*)d_in[2];
  const int*   cni        = (const int*)  d_in[4];
  const float* nW0 = (const float*)d_in[6];
  const float* nb0 = (const float*)d_in[7];
  const float* nW1 = (const float*)d_in[8];
  const float* nb1 = (const float*)d_in[9];
  const float* nW2 = (const float*)d_in[10];
  const float* nb2 = (const float*)d_in[11];
  const float* eW0 = (const float*)d_in[12];
  const float* eb0 = (const float*)d_in[13];
  const float* eW1 = (const float*)d_in[14];
  const float* eb1 = (const float*)d_in[15];
  const float* eW2 = (const float*)d_in[16];
  const float* eb2 = (const float*)d_in[17];

  float* out = (float*)d_out;
  float* node_factor = (float*)d_ws;

  node_mlp_kernel<<<BS * NA, 256, 0, stream>>>(
      node_types, node_enc, nW0, nb0, nW1, nb1, nW2, nb2, node_factor);

  edge_assemble_kernel<<<BS * NC, 256, 0, stream>>>(
      node_types, cni, edge_enc, eW0, eb0, eW1, eb1, eW2, eb2,
      node_factor, out);
}